// Round 14
// baseline (524.315 us; speedup 1.0000x reference)
//
#include <hip/hip_runtime.h>
#include <hip/hip_bf16.h>

typedef __attribute__((ext_vector_type(8))) short bf16x8;
typedef __attribute__((ext_vector_type(4))) float f32x4;
typedef __attribute__((ext_vector_type(16))) float f32x16;

#define GL_LDS16(g, l)                                                        \
  __builtin_amdgcn_global_load_lds((const __attribute__((address_space(1))) void*)(g), \
                                   (__attribute__((address_space(3))) void*)(l), 16, 0, 0)

// fused wait+barrier (single asm block: no memory op can slip between)
#define VM_BAR(N) asm volatile("s_waitcnt vmcnt(" #N ")\ns_barrier" ::: "memory")
#define LGKM_BAR() asm volatile("s_waitcnt lgkmcnt(0)\ns_barrier" ::: "memory")

__device__ __forceinline__ ushort f2bf(float f) {
  union { float f; unsigned u; } x; x.f = f;
  unsigned r = x.u + 0x7fffu + ((x.u >> 16) & 1u);
  return (ushort)(r >> 16);
}

// bijective XCD remap (m204)
__device__ __forceinline__ int xcd_remap(int bid, int nwg) {
  int q = nwg >> 3, r = nwg & 7;
  int xcd = bid & 7, idx = bid >> 3;
  return (xcd < r ? xcd * (q + 1) : r * (q + 1) + (xcd - r) * q) + idx;
}

// ---------------- fused f32 -> bf16 convert over 4 segments (vectorized) ----------------
__global__ void cvt4_kernel(const float* __restrict__ i0, const float* __restrict__ i1,
                            const float* __restrict__ i2, const float* __restrict__ i3,
                            int n0, int n1, int n2, int n3,
                            ushort* __restrict__ out) {
  int c1 = n0 >> 2, c2 = (n0 + n1) >> 2, c3 = (n0 + n1 + n2) >> 2,
      nt = (n0 + n1 + n2 + n3) >> 2;
  int i = blockIdx.x * blockDim.x + threadIdx.x;
  int stride = gridDim.x * blockDim.x;
  for (; i < nt; i += stride) {
    float4 v;
    if (i < c1) v = ((const float4*)i0)[i];
    else if (i < c2) v = ((const float4*)i1)[i - c1];
    else if (i < c3) v = ((const float4*)i2)[i - c2];
    else v = ((const float4*)i3)[i - c3];
    ushort4 o;
    o.x = f2bf(v.x); o.y = f2bf(v.y); o.z = f2bf(v.z); o.w = f2bf(v.w);
    ((ushort4*)out)[i] = o;
  }
}

// ---------------- LayerNorm: 4 waves/block, 1 wave per row ----------------
__global__ __launch_bounds__(256) void ln_kernel(
    const float* __restrict__ x1, const float* __restrict__ x2, int M1, int MT,
    const float* __restrict__ w, const float* __restrict__ b,
    ushort* __restrict__ out) {
  int row = blockIdx.x * 4 + (threadIdx.x >> 6);
  if (row >= MT) return;
  int lane = threadIdx.x & 63;
  const float* xr = (row < M1) ? x1 + (size_t)row * 768
                               : x2 + (size_t)(row - M1) * 768;
  float4 v[3];
  float s = 0.f, sq = 0.f;
#pragma unroll
  for (int i = 0; i < 3; i++) {
    v[i] = *(const float4*)(xr + i * 256 + lane * 4);
    s += v[i].x + v[i].y + v[i].z + v[i].w;
    sq += v[i].x * v[i].x + v[i].y * v[i].y + v[i].z * v[i].z + v[i].w * v[i].w;
  }
#pragma unroll
  for (int m = 1; m < 64; m <<= 1) { s += __shfl_xor(s, m); sq += __shfl_xor(sq, m); }
  float mean = s * (1.f / 768.f);
  float var = sq * (1.f / 768.f) - mean * mean;
  float rstd = rsqrtf(var + 1e-5f);
  ushort* orow = out + (size_t)row * 768;
#pragma unroll
  for (int i = 0; i < 3; i++) {
    int d = i * 256 + lane * 4;
    float4 wv = *(const float4*)(w + d);
    float4 bv = *(const float4*)(b + d);
    ushort4 o;
    o.x = f2bf((v[i].x - mean) * rstd * wv.x + bv.x);
    o.y = f2bf((v[i].y - mean) * rstd * wv.y + bv.y);
    o.z = f2bf((v[i].z - mean) * rstd * wv.z + bv.z);
    o.w = f2bf((v[i].w - mean) * rstd * wv.w + bv.w);
    *(ushort4*)(orow + d) = o;
  }
}

// ---------------- 128x128 GEMM: dbuf, 2-deep prefetch, counted vmcnt ----------------
// vmcnt(8) waits exactly tile tt (8 loads/thread, FIFO) while tile tt+1's
// 8 stay in flight; buffer overwritten only after lgkm-barrier.
#define GT_STAGE(buf, tstep)                                                   \
  do {                                                                         \
    int k0s = (tstep) << 6;                                                    \
    _Pragma("unroll") for (int i = 0; i < 4; i++) {                            \
      int row = i * 32 + srow;                                                 \
      int gch = schunk ^ (row & 7);                                            \
      GL_LDS16(A + (size_t)(rowBlk + row) * K + k0s + gch * 8,                 \
               &lA[buf][row * 64 + schunk * 8]);                               \
      GL_LDS16(W + (size_t)(colBlk + row) * K + k0s + gch * 8,                 \
               &lB[buf][row * 64 + schunk * 8]);                               \
    }                                                                          \
  } while (0)

#define GT_COMPUTE(cbuf)                                                       \
  do {                                                                         \
    _Pragma("unroll") for (int kk = 0; kk < 2; kk++) {                         \
      bf16x8 af[4], bfr[4];                                                    \
      _Pragma("unroll") for (int m = 0; m < 4; m++) {                          \
        int row = waveM * 64 + m * 16 + l15;                                   \
        af[m] = *(const bf16x8*)&lA[cbuf][row * 64 + ((kk * 32 + lg * 8) ^ ((row & 7) << 3))]; \
      }                                                                        \
      _Pragma("unroll") for (int cc = 0; cc < 4; cc++) {                       \
        int row = waveN * 64 + cc * 16 + l15;                                  \
        bfr[cc] = *(const bf16x8*)&lB[cbuf][row * 64 + ((kk * 32 + lg * 8) ^ ((row & 7) << 3))]; \
      }                                                                        \
      __builtin_amdgcn_s_setprio(1);                                           \
      _Pragma("unroll") for (int m = 0; m < 4; m++)                            \
        _Pragma("unroll") for (int cc = 0; cc < 4; cc++)                       \
          acc[m][cc] = __builtin_amdgcn_mfma_f32_16x16x32_bf16(af[m], bfr[cc], acc[m][cc], 0, 0, 0); \
      __builtin_amdgcn_s_setprio(0);                                           \
    }                                                                          \
  } while (0)

template <int MODE, int K, int NCOL>
__global__ __launch_bounds__(256) void gemm_tile(
    const ushort* __restrict__ A, const ushort* __restrict__ W,
    const float* __restrict__ bias, void* __restrict__ outp,
    int M, int N) {
  __shared__ ushort lA[2][128 * 64];
  __shared__ ushort lB[2][128 * 64];
  const int t = threadIdx.x;
  const int lane = t & 63, wave = t >> 6;
  const int l15 = lane & 15, lg = lane >> 4;
  const int waveM = wave >> 1, waveN = wave & 1;
  const int g = xcd_remap(blockIdx.x, gridDim.x);
  const int rowBlk = (g / NCOL) * 128;
  const int colBlk = (g % NCOL) * 128;
  const int srow = t >> 3;
  const int schunk = t & 7;

  f32x4 acc[4][4] = {};
  constexpr int nt = K >> 6;

  GT_STAGE(0, 0);
  GT_STAGE(1, 1);
#pragma unroll 1
  for (int tt = 0; tt < nt - 1; ++tt) {
    const int cur = tt & 1;
    VM_BAR(8);          // tile tt landed; tile tt+1's 8 loads stay in flight
    GT_COMPUTE(cur);
    LGKM_BAR();         // all waves done reading buf cur
    if (tt + 2 < nt) GT_STAGE(cur, tt + 2);
  }
  VM_BAR(0);
  GT_COMPUTE((nt - 1) & 1);

  const float qsc = (MODE == 0 && colBlk < 768) ? 0.18033688011112042f : 1.f;
#pragma unroll
  for (int m = 0; m < 4; m++) {
    int rowB = rowBlk + waveM * 64 + m * 16 + lg * 4;
#pragma unroll
    for (int c = 0; c < 4; c++) {
      int col = colBlk + waveN * 64 + c * 16 + l15;
      float bv = (MODE == 2) ? bias[col] : 0.f;
#pragma unroll
      for (int j = 0; j < 4; j++) {
        int r = rowB + j;
        if (r < M) {
          float v = acc[m][c][j] + bv;
          size_t idx = (size_t)r * N + col;
          if (MODE == 2) {
            float gl = 0.5f * v * (1.f + erff(v * 0.70710678118f));
            ((ushort*)outp)[idx] = f2bf(gl);
          } else {
            ((ushort*)outp)[idx] = f2bf(v * qsc);
          }
        }
      }
    }
  }
}

// ---------------- 64x128 GEMM: dbuf, 2-deep prefetch, vmcnt(6) ----------------
#define G64_STAGE(buf, tstep)                                                  \
  do {                                                                         \
    int k0s = (tstep) << 6;                                                    \
    _Pragma("unroll") for (int i = 0; i < 2; i++) {                            \
      int row = i * 32 + srow;                                                 \
      int gch = schunk ^ (row & 7);                                            \
      GL_LDS16(A + (size_t)(rowBlk + row) * K + k0s + gch * 8,                 \
               &lA[buf][row * 64 + schunk * 8]);                               \
    }                                                                          \
    _Pragma("unroll") for (int i = 0; i < 4; i++) {                            \
      int row = i * 32 + srow;                                                 \
      int gch = schunk ^ (row & 7);                                            \
      GL_LDS16(W + (size_t)(colBlk + row) * K + k0s + gch * 8,                 \
               &lB[buf][row * 64 + schunk * 8]);                               \
    }                                                                          \
  } while (0)

#define G64_COMPUTE(cbuf)                                                      \
  do {                                                                         \
    _Pragma("unroll") for (int kk = 0; kk < 2; kk++) {                         \
      bf16x8 af[2], bfr[4];                                                    \
      _Pragma("unroll") for (int m = 0; m < 2; m++) {                          \
        int row = waveM * 32 + m * 16 + l15;                                   \
        af[m] = *(const bf16x8*)&lA[cbuf][row * 64 + ((kk * 32 + lg * 8) ^ ((row & 7) << 3))]; \
      }                                                                        \
      _Pragma("unroll") for (int cc = 0; cc < 4; cc++) {                       \
        int row = waveN * 64 + cc * 16 + l15;                                  \
        bfr[cc] = *(const bf16x8*)&lB[cbuf][row * 64 + ((kk * 32 + lg * 8) ^ ((row & 7) << 3))]; \
      }                                                                        \
      __builtin_amdgcn_s_setprio(1);                                           \
      _Pragma("unroll") for (int m = 0; m < 2; m++)                            \
        _Pragma("unroll") for (int cc = 0; cc < 4; cc++)                       \
          acc[m][cc] = __builtin_amdgcn_mfma_f32_16x16x32_bf16(af[m], bfr[cc], acc[m][cc], 0, 0, 0); \
      __builtin_amdgcn_s_setprio(0);                                           \
    }                                                                          \
  } while (0)

template <int K, int NCOL>
__global__ __launch_bounds__(256) void gemm_tile64(
    const ushort* __restrict__ A, const ushort* __restrict__ W,
    const float* __restrict__ bias, const float* __restrict__ res1,
    const float* __restrict__ res2, int resSplit,
    float* __restrict__ outp, int M, int N) {
  __shared__ ushort lA[2][64 * 64];
  __shared__ ushort lB[2][128 * 64];
  const int t = threadIdx.x;
  const int lane = t & 63, wave = t >> 6;
  const int l15 = lane & 15, lg = lane >> 4;
  const int waveM = wave >> 1, waveN = wave & 1;
  const int g = xcd_remap(blockIdx.x, gridDim.x);
  const int rowBlk = (g / NCOL) * 64;
  const int colBlk = (g % NCOL) * 128;
  const int srow = t >> 3;
  const int schunk = t & 7;

  f32x4 acc[2][4] = {};
  constexpr int nt = K >> 6;

  G64_STAGE(0, 0);
  G64_STAGE(1, 1);
#pragma unroll 1
  for (int tt = 0; tt < nt - 1; ++tt) {
    const int cur = tt & 1;
    VM_BAR(6);
    G64_COMPUTE(cur);
    LGKM_BAR();
    if (tt + 2 < nt) G64_STAGE(cur, tt + 2);
  }
  VM_BAR(0);
  G64_COMPUTE((nt - 1) & 1);

#pragma unroll
  for (int m = 0; m < 2; m++) {
    int rowB = rowBlk + waveM * 32 + m * 16 + lg * 4;
#pragma unroll
    for (int c = 0; c < 4; c++) {
      int col = colBlk + waveN * 64 + c * 16 + l15;
      float bv = bias[col];
#pragma unroll
      for (int j = 0; j < 4; j++) {
        int r = rowB + j;
        if (r < M) {
          size_t idx = (size_t)r * N + col;
          float rv = (r < resSplit) ? res1[idx]
                                    : res2[(size_t)(r - resSplit) * N + col];
          outp[idx] = acc[m][c][j] + bv + rv;
        }
      }
    }
  }
}

// ---------------- prep: XCD-aligned grid (x = bhg, y = kv) ----------------
__global__ __launch_bounds__(256) void prep_kernel(
    const ushort* __restrict__ qkv, ushort* __restrict__ kt2,
    ushort* __restrict__ vt2, int N1, int N2, int nkv1, int nkv2, int M1) {
  __shared__ ushort lT[64 * 68];
  const int t = threadIdx.x;
  const int bhg = blockIdx.x;
  const int kv = blockIdx.y;
  const int part = bhg >= 96;
  const int bh = part ? bhg - 96 : bhg;
  const int N = part ? N2 : N1;
  const int nkv = part ? nkv2 : nkv1;
  if (kv >= nkv) return;
  const size_t rowbase = part ? (size_t)M1 : 0;
  const int b = bh / 12, h = bh % 12;
  const int k0 = kv * 64;
  const ushort* Kp = qkv + (rowbase + (size_t)b * N) * 2304 + 768 + h * 64;
  const ushort* Vp = Kp + 768;
  size_t tbase = (part ? (size_t)96 * nkv1 : 0) + (size_t)bh * nkv + kv;
  ushort* ktile = kt2 + tbase * 4096;
  ushort* vtile = vt2 + tbase * 4096;
#pragma unroll
  for (int p = 0; p < 2; p++) {
    int s = p * 256 + t;
    int chunk = s >> 6, krow = s & 63;
    ushort4 v0 = {0, 0, 0, 0}, v1 = {0, 0, 0, 0};
    if (k0 + krow < N) {
      const ushort* src = Kp + (size_t)(k0 + krow) * 2304 + chunk * 8;
      v0 = *(const ushort4*)src;
      v1 = *(const ushort4*)(src + 4);
    }
    *(ushort4*)&ktile[s * 8] = v0;
    *(ushort4*)&ktile[s * 8 + 4] = v1;
  }
#pragma unroll
  for (int p = 0; p < 2; p++) {
    int nl = p * 32 + (t >> 3);
    int dc = t & 7;
    ushort4 v0 = {0, 0, 0, 0}, v1 = {0, 0, 0, 0};
    if (k0 + nl < N) {
      const ushort* src = Vp + (size_t)(k0 + nl) * 2304 + dc * 8;
      v0 = *(const ushort4*)src;
      v1 = *(const ushort4*)(src + 4);
    }
    *(ushort4*)&lT[nl * 68 + dc * 8] = v0;
    *(ushort4*)&lT[nl * 68 + dc * 8 + 4] = v1;
  }
  __syncthreads();
#pragma unroll
  for (int p = 0; p < 2; p++) {
    int s = p * 256 + t;
    int kchunk = s >> 6, d = s & 63;
    ushort o[8];
#pragma unroll
    for (int j = 0; j < 8; j++) o[j] = lT[(kchunk * 8 + j) * 68 + d];
    *(ushort4*)&vtile[s * 8] = *(ushort4*)o;
    *(ushort4*)&vtile[s * 8 + 4] = *(ushort4*)(o + 4);
  }
}

// ---------------- Flash attention: no-max-tracking softmax ----------------
#define ATTN_STAGE(buf, kvi)                                                   \
  do {                                                                         \
    _Pragma("unroll") for (int p = 0; p < 2; p++) {                            \
      int s = p * 256 + t;                                                     \
      GL_LDS16(tK + (size_t)(kvi) * 4096 + s * 8, &lK[buf][s * 8]);            \
      GL_LDS16(tV + (size_t)(kvi) * 4096 + s * 8, &lV[buf][s * 8]);            \
    }                                                                          \
  } while (0)

__global__ __launch_bounds__(256) void attn_kernel(
    const ushort* __restrict__ qkv, const ushort* __restrict__ kt2,
    const ushort* __restrict__ vt2, ushort* __restrict__ o_out,
    int N1, int N2, int nkv1, int nkv2, int M1) {
  __shared__ ushort lK[2][4096];
  __shared__ ushort lV[2][4096];
  const int t = threadIdx.x;
  const int lane = t & 63, wave = t >> 6;
  const int l31 = lane & 31, hi = lane >> 5;
  const int bhg = blockIdx.x;
  const int part = bhg >= 96;
  const int bh = part ? bhg - 96 : bhg;
  const int N = part ? N2 : N1;
  const int nkv = part ? nkv2 : nkv1;
  const int qb = blockIdx.y * 128;
  if (qb >= N) return;
  const size_t rowbase = part ? (size_t)M1 : 0;
  const int b = bh / 12, h = bh % 12;
  const ushort* Qp = qkv + (rowbase + (size_t)b * N) * 2304 + h * 64;
  const size_t tboff = (part ? (size_t)96 * nkv1 : 0) + (size_t)bh * nkv;
  const ushort* tK = kt2 + tboff * 4096;
  const ushort* tV = vt2 + tboff * 4096;

  const int qrow = min(qb + wave * 32 + l31, N - 1);  // clamp; outputs guarded
  bf16x8 qf[4];
#pragma unroll
  for (int kc = 0; kc < 4; kc++)
    qf[kc] = *(const bf16x8*)(Qp + (size_t)qrow * 2304 + kc * 16 + hi * 8);

  union { unsigned u[4]; bf16x8 v; } ones;
#pragma unroll
  for (int i = 0; i < 4; i++) ones.u[i] = 0x3F803F80u;

  f32x16 oacc[2] = {};
  f32x16 osum = {};

  ATTN_STAGE(0, 0);
  __syncthreads();
  for (int kv = 0; kv < nkv; kv++) {
    int cur = kv & 1;
    if (kv + 1 < nkv) ATTN_STAGE(cur ^ 1, kv + 1);
    const bool fullTile = (kv * 64 + 64 <= N);
    f32x16 sacc0 = {}, sacc1 = {};
    __builtin_amdgcn_s_setprio(1);
#pragma unroll
    for (int kc = 0; kc < 4; kc++) {
      bf16x8 kf0 = *(const bf16x8*)&lK[cur][(((kc * 2 + hi) << 6) + l31) * 8];
      bf16x8 kf1 = *(const bf16x8*)&lK[cur][(((kc * 2 + hi) << 6) + 32 + l31) * 8];
      sacc0 = __builtin_amdgcn_mfma_f32_32x32x16_bf16(kf0, qf[kc], sacc0, 0, 0, 0);
      sacc1 = __builtin_amdgcn_mfma_f32_32x32x16_bf16(kf1, qf[kc], sacc1, 0, 0, 0);
    }
    __builtin_amdgcn_s_setprio(0);
    float z[32];
#pragma unroll
    for (int r = 0; r < 16; r++) { z[r] = sacc0[r]; z[16 + r] = sacc1[r]; }
    if (!fullTile) {
#pragma unroll
      for (int i = 0; i < 32; i++) {
        int kg = kv * 64 + (i >> 4) * 32 + (i & 3) + (((i & 15) >> 2) << 3) + (hi << 2);
        if (kg >= N) z[i] = -1e30f;
      }
    }
#pragma unroll
    for (int i = 0; i < 32; i++) z[i] = exp2f(z[i]);
#pragma unroll
    for (int kt = 0; kt < 2; kt++) {
      unsigned w0[4], w1[4];
#pragma unroll
      for (int rr = 0; rr < 4; rr++) {
        asm("v_cvt_pk_bf16_f32 %0, %1, %2" : "=v"(w0[rr]) : "v"(z[kt * 16 + 4 * rr]), "v"(z[kt * 16 + 4 * rr + 1]));
        asm("v_cvt_pk_bf16_f32 %0, %1, %2" : "=v"(w1[rr]) : "v"(z[kt * 16 + 4 * rr + 2]), "v"(z[kt * 16 + 4 * rr + 3]));
      }
#pragma unroll
      for (int kc2 = 0; kc2 < 2; kc2++) {
        unsigned ua = w0[2 * kc2], ub = w0[2 * kc2 + 1];
        unsigned uc = w1[2 * kc2], ud = w1[2 * kc2 + 1];
        asm("v_permlane32_swap_b32 %0, %1" : "+&v"(ua), "+v"(ub));
        asm("v_permlane32_swap_b32 %0, %1" : "+&v"(uc), "+v"(ud));
        union { unsigned u[4]; bf16x8 v; } pa;
        pa.u[0] = ua; pa.u[1] = uc; pa.u[2] = ub; pa.u[3] = ud;
        int kcg = kt * 2 + kc2;
        __builtin_amdgcn_s_setprio(1);
#pragma unroll
        for (int dt = 0; dt < 2; dt++) {
          bf16x8 vf = *(const bf16x8*)&lV[cur][(((kcg * 2 + hi) << 6) + dt * 32 + l31) * 8];
          oacc[dt] = __builtin_amdgcn_mfma_f32_32x32x16_bf16(pa.v, vf, oacc[dt], 0, 0, 0);
        }
        osum = __builtin_amdgcn_mfma_f32_32x32x16_bf16(pa.v, ones.v, osum, 0, 0, 0);
        __builtin_amdgcn_s_setprio(0);
      }
    }
    __syncthreads();
  }
#pragma unroll
  for (int r = 0; r < 16; r++) {
    int q = qb + wave * 32 + (r & 3) + ((r >> 2) << 3) + (hi << 2);
    if (q < N) {
      float inv;
      asm("v_rcp_f32 %0, %1" : "=v"(inv) : "v"(osum[r]));
      ushort* orow = o_out + (rowbase + (size_t)b * N + q) * 768 + h * 64;
      orow[l31] = f2bf(oacc[0][r] * inv);
      orow[32 + l31] = f2bf(oacc[1][r] * inv);
    }
  }
}

// ---------------- host-side orchestration (fused streams) ----------------
extern "C" void kernel_launch(void* const* d_in, const int* in_sizes, int n_in,
                              void* d_out, int out_size, void* d_ws, size_t ws_size,
                              hipStream_t stream) {
  const float* x1 = (const float*)d_in[0];
  const float* x2 = (const float*)d_in[1];
  const float* ln1_w = (const float*)d_in[2];
  const float* ln1_b = (const float*)d_in[3];
  const float* qkv_w = (const float*)d_in[4];
  const float* proj_w = (const float*)d_in[5];
  const float* proj_b = (const float*)d_in[6];
  const float* ln2_w = (const float*)d_in[7];
  const float* ln2_b = (const float*)d_in[8];
  const float* fc1_w = (const float*)d_in[9];
  const float* fc1_b = (const float*)d_in[10];
  const float* fc2_w = (const float*)d_in[11];
  const float* fc2_b = (const float*)d_in[12];
  float* out = (float*)d_out;

  const int N1 = 1370, N2 = 257;
  const int M1 = 8 * N1, M2 = 8 * N2;    // 10960, 2056
  const int MT = M1 + M2;                // 13016
  const int MPAD = 13056;                // 102*128 = 204*64
  const int nkv1 = 22, nkv2 = 5;

  char* ws = (char*)d_ws;
  ushort* wq = (ushort*)ws;   ws += (size_t)2304 * 768 * 2;
  ushort* wp = (ushort*)ws;   ws += (size_t)768 * 768 * 2;
  ushort* w1 = (ushort*)ws;   ws += (size_t)3072 * 768 * 2;
  ushort* w2 = (ushort*)ws;   ws += (size_t)768 * 3072 * 2;
  ushort* bufA = (ushort*)ws;   ws += (size_t)MPAD * 768 * 2;
  ushort* bufQKV = (ushort*)ws; ws += (size_t)MPAD * 2304 * 2;
  ushort* bufFF = (ushort*)ws;  ws += (size_t)MPAD * 3072 * 2;
  const size_t nTiles = (size_t)96 * (nkv1 + nkv2);
  ushort* kt2 = bufFF;
  ushort* vt2 = bufFF + nTiles * 4096;

  cvt4_kernel<<<2048, 256, 0, stream>>>(qkv_w, proj_w, fc1_w, fc2_w,
                                        2304 * 768, 768 * 768, 3072 * 768, 768 * 3072, wq);

  ln_kernel<<<(MT + 3) / 4, 256, 0, stream>>>(x1, x2, M1, MT, ln1_w, ln1_b, bufA);
  gemm_tile<0, 768, 18><<<(MPAD / 128) * 18, 256, 0, stream>>>(
      bufA, wq, nullptr, bufQKV, MT, 2304);
  prep_kernel<<<dim3(192, nkv1), 256, 0, stream>>>(bufQKV, kt2, vt2, N1, N2, nkv1, nkv2, M1);
  attn_kernel<<<dim3(192, 11), 256, 0, stream>>>(
      bufQKV, kt2, vt2, bufA, N1, N2, nkv1, nkv2, M1);
  gemm_tile64<768, 6><<<(MPAD / 64) * 6, 256, 0, stream>>>(
      bufA, wp, proj_b, x1, x2, M1, out, MT, 768);
  ln_kernel<<<(MT + 3) / 4, 256, 0, stream>>>(out, out, MT, MT, ln2_w, ln2_b, bufA);
  gemm_tile<2, 768, 24><<<(MPAD / 128) * 24, 256, 0, stream>>>(
      bufA, w1, fc1_b, bufFF, MT, 3072);
  gemm_tile64<3072, 6><<<(MPAD / 64) * 6, 256, 0, stream>>>(
      bufFF, w2, fc2_b, out, nullptr, MT, out, MT, 768);
}

// Round 15
// 476.174 us; speedup vs baseline: 1.1011x; 1.1011x over previous
//
#include <hip/hip_runtime.h>
#include <hip/hip_bf16.h>

typedef __attribute__((ext_vector_type(8))) short bf16x8;
typedef __attribute__((ext_vector_type(4))) float f32x4;
typedef __attribute__((ext_vector_type(16))) float f32x16;

#define GL_LDS16(g, l)                                                        \
  __builtin_amdgcn_global_load_lds((const __attribute__((address_space(1))) void*)(g), \
                                   (__attribute__((address_space(3))) void*)(l), 16, 0, 0)

__device__ __forceinline__ ushort f2bf(float f) {
  union { float f; unsigned u; } x; x.f = f;
  unsigned r = x.u + 0x7fffu + ((x.u >> 16) & 1u);
  return (ushort)(r >> 16);
}

// bijective XCD remap (m204)
__device__ __forceinline__ int xcd_remap(int bid, int nwg) {
  int q = nwg >> 3, r = nwg & 7;
  int xcd = bid & 7, idx = bid >> 3;
  return (xcd < r ? xcd * (q + 1) : r * (q + 1) + (xcd - r) * q) + idx;
}

// ---------------- fused f32 -> bf16 convert over 4 segments (vectorized) ----------------
__global__ void cvt4_kernel(const float* __restrict__ i0, const float* __restrict__ i1,
                            const float* __restrict__ i2, const float* __restrict__ i3,
                            int n0, int n1, int n2, int n3,
                            ushort* __restrict__ out) {
  int c1 = n0 >> 2, c2 = (n0 + n1) >> 2, c3 = (n0 + n1 + n2) >> 2,
      nt = (n0 + n1 + n2 + n3) >> 2;
  int i = blockIdx.x * blockDim.x + threadIdx.x;
  int stride = gridDim.x * blockDim.x;
  for (; i < nt; i += stride) {
    float4 v;
    if (i < c1) v = ((const float4*)i0)[i];
    else if (i < c2) v = ((const float4*)i1)[i - c1];
    else if (i < c3) v = ((const float4*)i2)[i - c2];
    else v = ((const float4*)i3)[i - c3];
    ushort4 o;
    o.x = f2bf(v.x); o.y = f2bf(v.y); o.z = f2bf(v.z); o.w = f2bf(v.w);
    ((ushort4*)out)[i] = o;
  }
}

// ---------------- LayerNorm: 4 waves/block, 1 wave per row ----------------
__global__ __launch_bounds__(256) void ln_kernel(
    const float* __restrict__ x1, const float* __restrict__ x2, int M1, int MT,
    const float* __restrict__ w, const float* __restrict__ b,
    ushort* __restrict__ out) {
  int row = blockIdx.x * 4 + (threadIdx.x >> 6);
  if (row >= MT) return;
  int lane = threadIdx.x & 63;
  const float* xr = (row < M1) ? x1 + (size_t)row * 768
                               : x2 + (size_t)(row - M1) * 768;
  float4 v[3];
  float s = 0.f, sq = 0.f;
#pragma unroll
  for (int i = 0; i < 3; i++) {
    v[i] = *(const float4*)(xr + i * 256 + lane * 4);
    s += v[i].x + v[i].y + v[i].z + v[i].w;
    sq += v[i].x * v[i].x + v[i].y * v[i].y + v[i].z * v[i].z + v[i].w * v[i].w;
  }
#pragma unroll
  for (int m = 1; m < 64; m <<= 1) { s += __shfl_xor(s, m); sq += __shfl_xor(sq, m); }
  float mean = s * (1.f / 768.f);
  float var = sq * (1.f / 768.f) - mean * mean;
  float rstd = rsqrtf(var + 1e-5f);
  ushort* orow = out + (size_t)row * 768;
#pragma unroll
  for (int i = 0; i < 3; i++) {
    int d = i * 256 + lane * 4;
    float4 wv = *(const float4*)(w + d);
    float4 bv = *(const float4*)(b + d);
    ushort4 o;
    o.x = f2bf((v[i].x - mean) * rstd * wv.x + bv.x);
    o.y = f2bf((v[i].y - mean) * rstd * wv.y + bv.y);
    o.z = f2bf((v[i].z - mean) * rstd * wv.z + bv.z);
    o.w = f2bf((v[i].w - mean) * rstd * wv.w + bv.w);
    *(ushort4*)(orow + d) = o;
  }
}

// ---------------- 128x128 GEMM (r13 structure: single-buffer, 2 barriers) ----------------
template <int MODE, int K, int NCOL>
__global__ __launch_bounds__(256) void gemm_tile(
    const ushort* __restrict__ A, const ushort* __restrict__ W,
    const float* __restrict__ bias, void* __restrict__ outp,
    int M, int N) {
  __shared__ ushort lA[128 * 64];
  __shared__ ushort lB[128 * 64];
  const int t = threadIdx.x;
  const int lane = t & 63, wave = t >> 6;
  const int l15 = lane & 15, lg = lane >> 4;
  const int waveM = wave >> 1, waveN = wave & 1;
  const int g = xcd_remap(blockIdx.x, gridDim.x);
  const int rowBlk = (g / NCOL) * 128;
  const int colBlk = (g % NCOL) * 128;
  const int srow = t >> 3;
  const int schunk = t & 7;

  f32x4 acc[4][4] = {};

#pragma unroll 1
  for (int k0 = 0; k0 < K; k0 += 64) {
    if (k0) __syncthreads();
#pragma unroll
    for (int i = 0; i < 4; i++) {
      int row = i * 32 + srow;
      int gch = schunk ^ (row & 7);
      GL_LDS16(A + (size_t)(rowBlk + row) * K + k0 + gch * 8,
               &lA[row * 64 + schunk * 8]);
      GL_LDS16(W + (size_t)(colBlk + row) * K + k0 + gch * 8,
               &lB[row * 64 + schunk * 8]);
    }
    __syncthreads();
#pragma unroll
    for (int kk = 0; kk < 2; kk++) {
      bf16x8 af[4], bfr[4];
#pragma unroll
      for (int m = 0; m < 4; m++) {
        int row = waveM * 64 + m * 16 + l15;
        af[m] = *(const bf16x8*)&lA[row * 64 + ((kk * 32 + lg * 8) ^ ((row & 7) << 3))];
      }
#pragma unroll
      for (int c = 0; c < 4; c++) {
        int row = waveN * 64 + c * 16 + l15;
        bfr[c] = *(const bf16x8*)&lB[row * 64 + ((kk * 32 + lg * 8) ^ ((row & 7) << 3))];
      }
      __builtin_amdgcn_s_setprio(1);
#pragma unroll
      for (int m = 0; m < 4; m++)
#pragma unroll
        for (int c = 0; c < 4; c++)
          acc[m][c] = __builtin_amdgcn_mfma_f32_16x16x32_bf16(af[m], bfr[c], acc[m][c], 0, 0, 0);
      __builtin_amdgcn_s_setprio(0);
    }
  }

  const float qsc = (MODE == 0 && colBlk < 768) ? 0.18033688011112042f : 1.f;
#pragma unroll
  for (int m = 0; m < 4; m++) {
    int rowB = rowBlk + waveM * 64 + m * 16 + lg * 4;
#pragma unroll
    for (int c = 0; c < 4; c++) {
      int col = colBlk + waveN * 64 + c * 16 + l15;
      float bv = (MODE == 2) ? bias[col] : 0.f;
#pragma unroll
      for (int j = 0; j < 4; j++) {
        int r = rowB + j;
        if (r < M) {
          float v = acc[m][c][j] + bv;
          size_t idx = (size_t)r * N + col;
          if (MODE == 2) {
            float gl = 0.5f * v * (1.f + erff(v * 0.70710678118f));
            ((ushort*)outp)[idx] = f2bf(gl);
          } else {
            ((ushort*)outp)[idx] = f2bf(v * qsc);
          }
        }
      }
    }
  }
}

// ---------------- 64x128 GEMM (r13 structure): proj / fc2 ----------------
template <int K, int NCOL>
__global__ __launch_bounds__(256) void gemm_tile64(
    const ushort* __restrict__ A, const ushort* __restrict__ W,
    const float* __restrict__ bias, const float* __restrict__ res1,
    const float* __restrict__ res2, int resSplit,
    float* __restrict__ outp, int M, int N) {
  __shared__ ushort lA[64 * 64];
  __shared__ ushort lB[128 * 64];
  const int t = threadIdx.x;
  const int lane = t & 63, wave = t >> 6;
  const int l15 = lane & 15, lg = lane >> 4;
  const int waveM = wave >> 1, waveN = wave & 1;
  const int g = xcd_remap(blockIdx.x, gridDim.x);
  const int rowBlk = (g / NCOL) * 64;
  const int colBlk = (g % NCOL) * 128;
  const int srow = t >> 3;
  const int schunk = t & 7;

  f32x4 acc[2][4] = {};

#pragma unroll 1
  for (int k0 = 0; k0 < K; k0 += 64) {
    if (k0) __syncthreads();
#pragma unroll
    for (int i = 0; i < 2; i++) {
      int row = i * 32 + srow;
      int gch = schunk ^ (row & 7);
      GL_LDS16(A + (size_t)(rowBlk + row) * K + k0 + gch * 8,
               &lA[row * 64 + schunk * 8]);
    }
#pragma unroll
    for (int i = 0; i < 4; i++) {
      int row = i * 32 + srow;
      int gch = schunk ^ (row & 7);
      GL_LDS16(W + (size_t)(colBlk + row) * K + k0 + gch * 8,
               &lB[row * 64 + schunk * 8]);
    }
    __syncthreads();
#pragma unroll
    for (int kk = 0; kk < 2; kk++) {
      bf16x8 af[2], bfr[4];
#pragma unroll
      for (int m = 0; m < 2; m++) {
        int row = waveM * 32 + m * 16 + l15;
        af[m] = *(const bf16x8*)&lA[row * 64 + ((kk * 32 + lg * 8) ^ ((row & 7) << 3))];
      }
#pragma unroll
      for (int c = 0; c < 4; c++) {
        int row = waveN * 64 + c * 16 + l15;
        bfr[c] = *(const bf16x8*)&lB[row * 64 + ((kk * 32 + lg * 8) ^ ((row & 7) << 3))];
      }
      __builtin_amdgcn_s_setprio(1);
#pragma unroll
      for (int m = 0; m < 2; m++)
#pragma unroll
        for (int c = 0; c < 4; c++)
          acc[m][c] = __builtin_amdgcn_mfma_f32_16x16x32_bf16(af[m], bfr[c], acc[m][c], 0, 0, 0);
      __builtin_amdgcn_s_setprio(0);
    }
  }

#pragma unroll
  for (int m = 0; m < 2; m++) {
    int rowB = rowBlk + waveM * 32 + m * 16 + lg * 4;
#pragma unroll
    for (int c = 0; c < 4; c++) {
      int col = colBlk + waveN * 64 + c * 16 + l15;
      float bv = bias[col];
#pragma unroll
      for (int j = 0; j < 4; j++) {
        int r = rowB + j;
        if (r < M) {
          size_t idx = (size_t)r * N + col;
          float rv = (r < resSplit) ? res1[idx]
                                    : res2[(size_t)(r - resSplit) * N + col];
          outp[idx] = acc[m][c][j] + bv + rv;
        }
      }
    }
  }
}

// ---------------- prep: XCD-aligned grid (x = bhg, y = kv) ----------------
__global__ __launch_bounds__(256) void prep_kernel(
    const ushort* __restrict__ qkv, ushort* __restrict__ kt2,
    ushort* __restrict__ vt2, int N1, int N2, int nkv1, int nkv2, int M1) {
  __shared__ ushort lT[64 * 68];
  const int t = threadIdx.x;
  const int bhg = blockIdx.x;
  const int kv = blockIdx.y;
  const int part = bhg >= 96;
  const int bh = part ? bhg - 96 : bhg;
  const int N = part ? N2 : N1;
  const int nkv = part ? nkv2 : nkv1;
  if (kv >= nkv) return;
  const size_t rowbase = part ? (size_t)M1 : 0;
  const int b = bh / 12, h = bh % 12;
  const int k0 = kv * 64;
  const ushort* Kp = qkv + (rowbase + (size_t)b * N) * 2304 + 768 + h * 64;
  const ushort* Vp = Kp + 768;
  size_t tbase = (part ? (size_t)96 * nkv1 : 0) + (size_t)bh * nkv + kv;
  ushort* ktile = kt2 + tbase * 4096;
  ushort* vtile = vt2 + tbase * 4096;
#pragma unroll
  for (int p = 0; p < 2; p++) {
    int s = p * 256 + t;
    int chunk = s >> 6, krow = s & 63;
    ushort4 v0 = {0, 0, 0, 0}, v1 = {0, 0, 0, 0};
    if (k0 + krow < N) {
      const ushort* src = Kp + (size_t)(k0 + krow) * 2304 + chunk * 8;
      v0 = *(const ushort4*)src;
      v1 = *(const ushort4*)(src + 4);
    }
    *(ushort4*)&ktile[s * 8] = v0;
    *(ushort4*)&ktile[s * 8 + 4] = v1;
  }
#pragma unroll
  for (int p = 0; p < 2; p++) {
    int nl = p * 32 + (t >> 3);
    int dc = t & 7;
    ushort4 v0 = {0, 0, 0, 0}, v1 = {0, 0, 0, 0};
    if (k0 + nl < N) {
      const ushort* src = Vp + (size_t)(k0 + nl) * 2304 + dc * 8;
      v0 = *(const ushort4*)src;
      v1 = *(const ushort4*)(src + 4);
    }
    *(ushort4*)&lT[nl * 68 + dc * 8] = v0;
    *(ushort4*)&lT[nl * 68 + dc * 8 + 4] = v1;
  }
  __syncthreads();
#pragma unroll
  for (int p = 0; p < 2; p++) {
    int s = p * 256 + t;
    int kchunk = s >> 6, d = s & 63;
    ushort o[8];
#pragma unroll
    for (int j = 0; j < 8; j++) o[j] = lT[(kchunk * 8 + j) * 68 + d];
    *(ushort4*)&vtile[s * 8] = *(ushort4*)o;
    *(ushort4*)&vtile[s * 8 + 4] = *(ushort4*)(o + 4);
  }
}

// ---------------- Flash attention: barrier-free, L2-direct K/V reads ----------------
// K/V prep tiles are XCD-L2-resident (352 KB/bh, shared by this XCD's 11
// q-blocks). Fragment loads hit two contiguous 512B segments per wave
// (chunk-major tile layout) - fully coalesced. No LDS, no __syncthreads:
// pure per-wave dataflow; compiler hoists V loads under softmax VALU.
__global__ __launch_bounds__(256) void attn_kernel(
    const ushort* __restrict__ qkv, const ushort* __restrict__ kt2,
    const ushort* __restrict__ vt2, ushort* __restrict__ o_out,
    int N1, int N2, int nkv1, int nkv2, int M1) {
  const int t = threadIdx.x;
  const int lane = t & 63, wave = t >> 6;
  const int l31 = lane & 31, hi = lane >> 5;
  const int bhg = blockIdx.x;
  const int part = bhg >= 96;
  const int bh = part ? bhg - 96 : bhg;
  const int N = part ? N2 : N1;
  const int nkv = part ? nkv2 : nkv1;
  const int qb = blockIdx.y * 128;
  if (qb >= N) return;
  const size_t rowbase = part ? (size_t)M1 : 0;
  const int b = bh / 12, h = bh % 12;
  const ushort* Qp = qkv + (rowbase + (size_t)b * N) * 2304 + h * 64;
  const size_t tboff = (part ? (size_t)96 * nkv1 : 0) + (size_t)bh * nkv;
  const ushort* tK = kt2 + tboff * 4096;
  const ushort* tV = vt2 + tboff * 4096;

  const int qrow = min(qb + wave * 32 + l31, N - 1);  // clamp; outputs guarded
  bf16x8 qf[4];
#pragma unroll
  for (int kc = 0; kc < 4; kc++)
    qf[kc] = *(const bf16x8*)(Qp + (size_t)qrow * 2304 + kc * 16 + hi * 8);

  union { unsigned u[4]; bf16x8 v; } ones;
#pragma unroll
  for (int i = 0; i < 4; i++) ones.u[i] = 0x3F803F80u;

  f32x16 oacc[2] = {};
  f32x16 osum = {};

  for (int kv = 0; kv < nkv; kv++) {
    const ushort* Kt = tK + (size_t)kv * 4096;
    const ushort* Vt = tV + (size_t)kv * 4096;
    const bool fullTile = (kv * 64 + 64 <= N);
    f32x16 sacc0 = {}, sacc1 = {};
    __builtin_amdgcn_s_setprio(1);
#pragma unroll
    for (int kc = 0; kc < 4; kc++) {
      bf16x8 kf0 = *(const bf16x8*)&Kt[(((kc * 2 + hi) << 6) + l31) * 8];
      bf16x8 kf1 = *(const bf16x8*)&Kt[(((kc * 2 + hi) << 6) + 32 + l31) * 8];
      sacc0 = __builtin_amdgcn_mfma_f32_32x32x16_bf16(kf0, qf[kc], sacc0, 0, 0, 0);
      sacc1 = __builtin_amdgcn_mfma_f32_32x32x16_bf16(kf1, qf[kc], sacc1, 0, 0, 0);
    }
    __builtin_amdgcn_s_setprio(0);
    float z[32];
#pragma unroll
    for (int r = 0; r < 16; r++) { z[r] = sacc0[r]; z[16 + r] = sacc1[r]; }
    if (!fullTile) {
#pragma unroll
      for (int i = 0; i < 32; i++) {
        int kg = kv * 64 + (i >> 4) * 32 + (i & 3) + (((i & 15) >> 2) << 3) + (hi << 2);
        if (kg >= N) z[i] = -1e30f;
      }
    }
#pragma unroll
    for (int i = 0; i < 32; i++) z[i] = exp2f(z[i]);
#pragma unroll
    for (int kt = 0; kt < 2; kt++) {
      unsigned w0[4], w1[4];
#pragma unroll
      for (int rr = 0; rr < 4; rr++) {
        asm("v_cvt_pk_bf16_f32 %0, %1, %2" : "=v"(w0[rr]) : "v"(z[kt * 16 + 4 * rr]), "v"(z[kt * 16 + 4 * rr + 1]));
        asm("v_cvt_pk_bf16_f32 %0, %1, %2" : "=v"(w1[rr]) : "v"(z[kt * 16 + 4 * rr + 2]), "v"(z[kt * 16 + 4 * rr + 3]));
      }
#pragma unroll
      for (int kc2 = 0; kc2 < 2; kc2++) {
        unsigned ua = w0[2 * kc2], ub = w0[2 * kc2 + 1];
        unsigned uc = w1[2 * kc2], ud = w1[2 * kc2 + 1];
        asm("v_permlane32_swap_b32 %0, %1" : "+&v"(ua), "+v"(ub));
        asm("v_permlane32_swap_b32 %0, %1" : "+&v"(uc), "+v"(ud));
        union { unsigned u[4]; bf16x8 v; } pa;
        pa.u[0] = ua; pa.u[1] = uc; pa.u[2] = ub; pa.u[3] = ud;
        int kcg = kt * 2 + kc2;
        __builtin_amdgcn_s_setprio(1);
#pragma unroll
        for (int dt = 0; dt < 2; dt++) {
          bf16x8 vf = *(const bf16x8*)&Vt[(((kcg * 2 + hi) << 6) + dt * 32 + l31) * 8];
          oacc[dt] = __builtin_amdgcn_mfma_f32_32x32x16_bf16(pa.v, vf, oacc[dt], 0, 0, 0);
        }
        osum = __builtin_amdgcn_mfma_f32_32x32x16_bf16(pa.v, ones.v, osum, 0, 0, 0);
        __builtin_amdgcn_s_setprio(0);
      }
    }
  }
#pragma unroll
  for (int r = 0; r < 16; r++) {
    int q = qb + wave * 32 + (r & 3) + ((r >> 2) << 3) + (hi << 2);
    if (q < N) {
      float inv;
      asm("v_rcp_f32 %0, %1" : "=v"(inv) : "v"(osum[r]));
      ushort* orow = o_out + (rowbase + (size_t)b * N + q) * 768 + h * 64;
      orow[l31] = f2bf(oacc[0][r] * inv);
      orow[32 + l31] = f2bf(oacc[1][r] * inv);
    }
  }
}

// ---------------- host-side orchestration (fused streams) ----------------
extern "C" void kernel_launch(void* const* d_in, const int* in_sizes, int n_in,
                              void* d_out, int out_size, void* d_ws, size_t ws_size,
                              hipStream_t stream) {
  const float* x1 = (const float*)d_in[0];
  const float* x2 = (const float*)d_in[1];
  const float* ln1_w = (const float*)d_in[2];
  const float* ln1_b = (const float*)d_in[3];
  const float* qkv_w = (const float*)d_in[4];
  const float* proj_w = (const float*)d_in[5];
  const float* proj_b = (const float*)d_in[6];
  const float* ln2_w = (const float*)d_in[7];
  const float* ln2_b = (const float*)d_in[8];
  const float* fc1_w = (const float*)d_in[9];
  const float* fc1_b = (const float*)d_in[10];
  const float* fc2_w = (const float*)d_in[11];
  const float* fc2_b = (const float*)d_in[12];
  float* out = (float*)d_out;

  const int N1 = 1370, N2 = 257;
  const int M1 = 8 * N1, M2 = 8 * N2;    // 10960, 2056
  const int MT = M1 + M2;                // 13016
  const int MPAD = 13056;                // 102*128 = 204*64
  const int nkv1 = 22, nkv2 = 5;

  char* ws = (char*)d_ws;
  ushort* wq = (ushort*)ws;   ws += (size_t)2304 * 768 * 2;
  ushort* wp = (ushort*)ws;   ws += (size_t)768 * 768 * 2;
  ushort* w1 = (ushort*)ws;   ws += (size_t)3072 * 768 * 2;
  ushort* w2 = (ushort*)ws;   ws += (size_t)768 * 3072 * 2;
  ushort* bufA = (ushort*)ws;   ws += (size_t)MPAD * 768 * 2;
  ushort* bufQKV = (ushort*)ws; ws += (size_t)MPAD * 2304 * 2;
  ushort* bufFF = (ushort*)ws;  ws += (size_t)MPAD * 3072 * 2;
  const size_t nTiles = (size_t)96 * (nkv1 + nkv2);
  ushort* kt2 = bufFF;
  ushort* vt2 = bufFF + nTiles * 4096;

  cvt4_kernel<<<2048, 256, 0, stream>>>(qkv_w, proj_w, fc1_w, fc2_w,
                                        2304 * 768, 768 * 768, 3072 * 768, 768 * 3072, wq);

  ln_kernel<<<(MT + 3) / 4, 256, 0, stream>>>(x1, x2, M1, MT, ln1_w, ln1_b, bufA);
  gemm_tile<0, 768, 18><<<(MPAD / 128) * 18, 256, 0, stream>>>(
      bufA, wq, nullptr, bufQKV, MT, 2304);
  prep_kernel<<<dim3(192, nkv1), 256, 0, stream>>>(bufQKV, kt2, vt2, N1, N2, nkv1, nkv2, M1);
  attn_kernel<<<dim3(192, 11), 256, 0, stream>>>(
      bufQKV, kt2, vt2, bufA, N1, N2, nkv1, nkv2, M1);
  gemm_tile64<768, 6><<<(MPAD / 64) * 6, 256, 0, stream>>>(
      bufA, wp, proj_b, x1, x2, M1, out, MT, 768);
  ln_kernel<<<(MT + 3) / 4, 256, 0, stream>>>(out, out, MT, MT, ln2_w, ln2_b, bufA);
  gemm_tile<2, 768, 24><<<(MPAD / 128) * 24, 256, 0, stream>>>(
      bufA, w1, fc1_b, bufFF, MT, 3072);
  gemm_tile64<3072, 6><<<(MPAD / 64) * 6, 256, 0, stream>>>(
      bufFF, w2, fc2_b, out, nullptr, MT, out, MT, 768);
}

// Round 16
// 434.760 us; speedup vs baseline: 1.2060x; 1.0953x over previous
//
#include <hip/hip_runtime.h>
#include <hip/hip_bf16.h>

typedef __attribute__((ext_vector_type(8))) short bf16x8;
typedef __attribute__((ext_vector_type(4))) float f32x4;
typedef __attribute__((ext_vector_type(16))) float f32x16;

#define GL_LDS16(g, l)                                                        \
  __builtin_amdgcn_global_load_lds((const __attribute__((address_space(1))) void*)(g), \
                                   (__attribute__((address_space(3))) void*)(l), 16, 0, 0)

__device__ __forceinline__ ushort f2bf(float f) {
  union { float f; unsigned u; } x; x.f = f;
  unsigned r = x.u + 0x7fffu + ((x.u >> 16) & 1u);
  return (ushort)(r >> 16);
}

// bijective XCD remap (m204)
__device__ __forceinline__ int xcd_remap(int bid, int nwg) {
  int q = nwg >> 3, r = nwg & 7;
  int xcd = bid & 7, idx = bid >> 3;
  return (xcd < r ? xcd * (q + 1) : r * (q + 1) + (xcd - r) * q) + idx;
}

// ---------------- fused f32 -> bf16 convert over 4 segments (vectorized) ----------------
__global__ void cvt4_kernel(const float* __restrict__ i0, const float* __restrict__ i1,
                            const float* __restrict__ i2, const float* __restrict__ i3,
                            int n0, int n1, int n2, int n3,
                            ushort* __restrict__ out) {
  int c1 = n0 >> 2, c2 = (n0 + n1) >> 2, c3 = (n0 + n1 + n2) >> 2,
      nt = (n0 + n1 + n2 + n3) >> 2;
  int i = blockIdx.x * blockDim.x + threadIdx.x;
  int stride = gridDim.x * blockDim.x;
  for (; i < nt; i += stride) {
    float4 v;
    if (i < c1) v = ((const float4*)i0)[i];
    else if (i < c2) v = ((const float4*)i1)[i - c1];
    else if (i < c3) v = ((const float4*)i2)[i - c2];
    else v = ((const float4*)i3)[i - c3];
    ushort4 o;
    o.x = f2bf(v.x); o.y = f2bf(v.y); o.z = f2bf(v.z); o.w = f2bf(v.w);
    ((ushort4*)out)[i] = o;
  }
}

// ---------------- LayerNorm: 4 waves/block, 1 wave per row ----------------
__global__ __launch_bounds__(256) void ln_kernel(
    const float* __restrict__ x1, const float* __restrict__ x2, int M1, int MT,
    const float* __restrict__ w, const float* __restrict__ b,
    ushort* __restrict__ out) {
  int row = blockIdx.x * 4 + (threadIdx.x >> 6);
  if (row >= MT) return;
  int lane = threadIdx.x & 63;
  const float* xr = (row < M1) ? x1 + (size_t)row * 768
                               : x2 + (size_t)(row - M1) * 768;
  float4 v[3];
  float s = 0.f, sq = 0.f;
#pragma unroll
  for (int i = 0; i < 3; i++) {
    v[i] = *(const float4*)(xr + i * 256 + lane * 4);
    s += v[i].x + v[i].y + v[i].z + v[i].w;
    sq += v[i].x * v[i].x + v[i].y * v[i].y + v[i].z * v[i].z + v[i].w * v[i].w;
  }
#pragma unroll
  for (int m = 1; m < 64; m <<= 1) { s += __shfl_xor(s, m); sq += __shfl_xor(sq, m); }
  float mean = s * (1.f / 768.f);
  float var = sq * (1.f / 768.f) - mean * mean;
  float rstd = rsqrtf(var + 1e-5f);
  ushort* orow = out + (size_t)row * 768;
#pragma unroll
  for (int i = 0; i < 3; i++) {
    int d = i * 256 + lane * 4;
    float4 wv = *(const float4*)(w + d);
    float4 bv = *(const float4*)(b + d);
    ushort4 o;
    o.x = f2bf((v[i].x - mean) * rstd * wv.x + bv.x);
    o.y = f2bf((v[i].y - mean) * rstd * wv.y + bv.y);
    o.z = f2bf((v[i].z - mean) * rstd * wv.z + bv.z);
    o.w = f2bf((v[i].w - mean) * rstd * wv.w + bv.w);
    *(ushort4*)(orow + d) = o;
  }
}

// ---------------- 128x128 GEMM: 8 waves of 32x64 (register-residency fix) ----------------
// Same tile, same single-buffer 2-barrier loop, same both-sides swizzle;
// acc drops 64->32 AGPR per wave -> ~5 waves/SIMD resident (was 3).
template <int MODE, int K, int NCOL>
__global__ __launch_bounds__(512) void gemm_tile(
    const ushort* __restrict__ A, const ushort* __restrict__ W,
    const float* __restrict__ bias, void* __restrict__ outp,
    int M, int N) {
  __shared__ ushort lA[128 * 64];
  __shared__ ushort lB[128 * 64];
  const int t = threadIdx.x;
  const int lane = t & 63, wave = t >> 6;          // 8 waves
  const int l15 = lane & 15, lg = lane >> 4;
  const int waveM = wave >> 1, waveN = wave & 1;   // 4 x 2
  const int g = xcd_remap(blockIdx.x, gridDim.x);
  const int rowBlk = (g / NCOL) * 128;
  const int colBlk = (g % NCOL) * 128;
  const int srow = t >> 3;                         // 0..63
  const int schunk = t & 7;

  f32x4 acc[2][4] = {};

#pragma unroll 1
  for (int k0 = 0; k0 < K; k0 += 64) {
    if (k0) __syncthreads();
#pragma unroll
    for (int i = 0; i < 2; i++) {
      int row = i * 64 + srow;
      int gch = schunk ^ (row & 7);
      GL_LDS16(A + (size_t)(rowBlk + row) * K + k0 + gch * 8,
               &lA[row * 64 + schunk * 8]);
      GL_LDS16(W + (size_t)(colBlk + row) * K + k0 + gch * 8,
               &lB[row * 64 + schunk * 8]);
    }
    __syncthreads();
#pragma unroll
    for (int kk = 0; kk < 2; kk++) {
      bf16x8 af[2], bfr[4];
#pragma unroll
      for (int m = 0; m < 2; m++) {
        int row = waveM * 32 + m * 16 + l15;
        af[m] = *(const bf16x8*)&lA[row * 64 + ((kk * 32 + lg * 8) ^ ((row & 7) << 3))];
      }
#pragma unroll
      for (int c = 0; c < 4; c++) {
        int row = waveN * 64 + c * 16 + l15;
        bfr[c] = *(const bf16x8*)&lB[row * 64 + ((kk * 32 + lg * 8) ^ ((row & 7) << 3))];
      }
      __builtin_amdgcn_s_setprio(1);
#pragma unroll
      for (int m = 0; m < 2; m++)
#pragma unroll
        for (int c = 0; c < 4; c++)
          acc[m][c] = __builtin_amdgcn_mfma_f32_16x16x32_bf16(af[m], bfr[c], acc[m][c], 0, 0, 0);
      __builtin_amdgcn_s_setprio(0);
    }
  }

  const float qsc = (MODE == 0 && colBlk < 768) ? 0.18033688011112042f : 1.f;
#pragma unroll
  for (int m = 0; m < 2; m++) {
    int rowB = rowBlk + waveM * 32 + m * 16 + lg * 4;
#pragma unroll
    for (int c = 0; c < 4; c++) {
      int col = colBlk + waveN * 64 + c * 16 + l15;
      float bv = (MODE == 2) ? bias[col] : 0.f;
#pragma unroll
      for (int j = 0; j < 4; j++) {
        int r = rowB + j;
        if (r < M) {
          float v = acc[m][c][j] + bv;
          size_t idx = (size_t)r * N + col;
          if (MODE == 2) {
            float gl = 0.5f * v * (1.f + erff(v * 0.70710678118f));
            ((ushort*)outp)[idx] = f2bf(gl);
          } else {
            ((ushort*)outp)[idx] = f2bf(v * qsc);
          }
        }
      }
    }
  }
}

// ---------------- 64x128 GEMM (r13 structure): proj / fc2 ----------------
template <int K, int NCOL>
__global__ __launch_bounds__(256) void gemm_tile64(
    const ushort* __restrict__ A, const ushort* __restrict__ W,
    const float* __restrict__ bias, const float* __restrict__ res1,
    const float* __restrict__ res2, int resSplit,
    float* __restrict__ outp, int M, int N) {
  __shared__ ushort lA[64 * 64];
  __shared__ ushort lB[128 * 64];
  const int t = threadIdx.x;
  const int lane = t & 63, wave = t >> 6;
  const int l15 = lane & 15, lg = lane >> 4;
  const int waveM = wave >> 1, waveN = wave & 1;
  const int g = xcd_remap(blockIdx.x, gridDim.x);
  const int rowBlk = (g / NCOL) * 64;
  const int colBlk = (g % NCOL) * 128;
  const int srow = t >> 3;
  const int schunk = t & 7;

  f32x4 acc[2][4] = {};

#pragma unroll 1
  for (int k0 = 0; k0 < K; k0 += 64) {
    if (k0) __syncthreads();
#pragma unroll
    for (int i = 0; i < 2; i++) {
      int row = i * 32 + srow;
      int gch = schunk ^ (row & 7);
      GL_LDS16(A + (size_t)(rowBlk + row) * K + k0 + gch * 8,
               &lA[row * 64 + schunk * 8]);
    }
#pragma unroll
    for (int i = 0; i < 4; i++) {
      int row = i * 32 + srow;
      int gch = schunk ^ (row & 7);
      GL_LDS16(W + (size_t)(colBlk + row) * K + k0 + gch * 8,
               &lB[row * 64 + schunk * 8]);
    }
    __syncthreads();
#pragma unroll
    for (int kk = 0; kk < 2; kk++) {
      bf16x8 af[2], bfr[4];
#pragma unroll
      for (int m = 0; m < 2; m++) {
        int row = waveM * 32 + m * 16 + l15;
        af[m] = *(const bf16x8*)&lA[row * 64 + ((kk * 32 + lg * 8) ^ ((row & 7) << 3))];
      }
#pragma unroll
      for (int c = 0; c < 4; c++) {
        int row = waveN * 64 + c * 16 + l15;
        bfr[c] = *(const bf16x8*)&lB[row * 64 + ((kk * 32 + lg * 8) ^ ((row & 7) << 3))];
      }
      __builtin_amdgcn_s_setprio(1);
#pragma unroll
      for (int m = 0; m < 2; m++)
#pragma unroll
        for (int c = 0; c < 4; c++)
          acc[m][c] = __builtin_amdgcn_mfma_f32_16x16x32_bf16(af[m], bfr[c], acc[m][c], 0, 0, 0);
      __builtin_amdgcn_s_setprio(0);
    }
  }

#pragma unroll
  for (int m = 0; m < 2; m++) {
    int rowB = rowBlk + waveM * 32 + m * 16 + lg * 4;
#pragma unroll
    for (int c = 0; c < 4; c++) {
      int col = colBlk + waveN * 64 + c * 16 + l15;
      float bv = bias[col];
#pragma unroll
      for (int j = 0; j < 4; j++) {
        int r = rowB + j;
        if (r < M) {
          size_t idx = (size_t)r * N + col;
          float rv = (r < resSplit) ? res1[idx]
                                    : res2[(size_t)(r - resSplit) * N + col];
          outp[idx] = acc[m][c][j] + bv + rv;
        }
      }
    }
  }
}

// ---------------- prep: XCD-aligned grid (x = bhg, y = kv) ----------------
__global__ __launch_bounds__(256) void prep_kernel(
    const ushort* __restrict__ qkv, ushort* __restrict__ kt2,
    ushort* __restrict__ vt2, int N1, int N2, int nkv1, int nkv2, int M1) {
  __shared__ ushort lT[64 * 68];
  const int t = threadIdx.x;
  const int bhg = blockIdx.x;
  const int kv = blockIdx.y;
  const int part = bhg >= 96;
  const int bh = part ? bhg - 96 : bhg;
  const int N = part ? N2 : N1;
  const int nkv = part ? nkv2 : nkv1;
  if (kv >= nkv) return;
  const size_t rowbase = part ? (size_t)M1 : 0;
  const int b = bh / 12, h = bh % 12;
  const int k0 = kv * 64;
  const ushort* Kp = qkv + (rowbase + (size_t)b * N) * 2304 + 768 + h * 64;
  const ushort* Vp = Kp + 768;
  size_t tbase = (part ? (size_t)96 * nkv1 : 0) + (size_t)bh * nkv + kv;
  ushort* ktile = kt2 + tbase * 4096;
  ushort* vtile = vt2 + tbase * 4096;
#pragma unroll
  for (int p = 0; p < 2; p++) {
    int s = p * 256 + t;
    int chunk = s >> 6, krow = s & 63;
    ushort4 v0 = {0, 0, 0, 0}, v1 = {0, 0, 0, 0};
    if (k0 + krow < N) {
      const ushort* src = Kp + (size_t)(k0 + krow) * 2304 + chunk * 8;
      v0 = *(const ushort4*)src;
      v1 = *(const ushort4*)(src + 4);
    }
    *(ushort4*)&ktile[s * 8] = v0;
    *(ushort4*)&ktile[s * 8 + 4] = v1;
  }
#pragma unroll
  for (int p = 0; p < 2; p++) {
    int nl = p * 32 + (t >> 3);
    int dc = t & 7;
    ushort4 v0 = {0, 0, 0, 0}, v1 = {0, 0, 0, 0};
    if (k0 + nl < N) {
      const ushort* src = Vp + (size_t)(k0 + nl) * 2304 + dc * 8;
      v0 = *(const ushort4*)src;
      v1 = *(const ushort4*)(src + 4);
    }
    *(ushort4*)&lT[nl * 68 + dc * 8] = v0;
    *(ushort4*)&lT[nl * 68 + dc * 8 + 4] = v1;
  }
  __syncthreads();
#pragma unroll
  for (int p = 0; p < 2; p++) {
    int s = p * 256 + t;
    int kchunk = s >> 6, d = s & 63;
    ushort o[8];
#pragma unroll
    for (int j = 0; j < 8; j++) o[j] = lT[(kchunk * 8 + j) * 68 + d];
    *(ushort4*)&vtile[s * 8] = *(ushort4*)o;
    *(ushort4*)&vtile[s * 8 + 4] = *(ushort4*)(o + 4);
  }
}

// ---------------- Flash attention: r13 structure (LDS dbuf, no-max softmax) ----------------
#define ATTN_STAGE(buf, kvi)                                                   \
  do {                                                                         \
    _Pragma("unroll") for (int p = 0; p < 2; p++) {                            \
      int s = p * 256 + t;                                                     \
      GL_LDS16(tK + (size_t)(kvi) * 4096 + s * 8, &lK[buf][s * 8]);            \
      GL_LDS16(tV + (size_t)(kvi) * 4096 + s * 8, &lV[buf][s * 8]);            \
    }                                                                          \
  } while (0)

__global__ __launch_bounds__(256) void attn_kernel(
    const ushort* __restrict__ qkv, const ushort* __restrict__ kt2,
    const ushort* __restrict__ vt2, ushort* __restrict__ o_out,
    int N1, int N2, int nkv1, int nkv2, int M1) {
  __shared__ ushort lK[2][4096];
  __shared__ ushort lV[2][4096];
  const int t = threadIdx.x;
  const int lane = t & 63, wave = t >> 6;
  const int l31 = lane & 31, hi = lane >> 5;
  const int bhg = blockIdx.x;
  const int part = bhg >= 96;
  const int bh = part ? bhg - 96 : bhg;
  const int N = part ? N2 : N1;
  const int nkv = part ? nkv2 : nkv1;
  const int qb = blockIdx.y * 128;
  if (qb >= N) return;
  const size_t rowbase = part ? (size_t)M1 : 0;
  const int b = bh / 12, h = bh % 12;
  const ushort* Qp = qkv + (rowbase + (size_t)b * N) * 2304 + h * 64;
  const size_t tboff = (part ? (size_t)96 * nkv1 : 0) + (size_t)bh * nkv;
  const ushort* tK = kt2 + tboff * 4096;
  const ushort* tV = vt2 + tboff * 4096;

  const int qrow = min(qb + wave * 32 + l31, N - 1);  // clamp; outputs guarded
  bf16x8 qf[4];
#pragma unroll
  for (int kc = 0; kc < 4; kc++)
    qf[kc] = *(const bf16x8*)(Qp + (size_t)qrow * 2304 + kc * 16 + hi * 8);

  union { unsigned u[4]; bf16x8 v; } ones;
#pragma unroll
  for (int i = 0; i < 4; i++) ones.u[i] = 0x3F803F80u;

  f32x16 oacc[2] = {};
  f32x16 osum = {};

  ATTN_STAGE(0, 0);
  __syncthreads();
  for (int kv = 0; kv < nkv; kv++) {
    int cur = kv & 1;
    if (kv + 1 < nkv) ATTN_STAGE(cur ^ 1, kv + 1);
    const bool fullTile = (kv * 64 + 64 <= N);
    f32x16 sacc0 = {}, sacc1 = {};
    __builtin_amdgcn_s_setprio(1);
#pragma unroll
    for (int kc = 0; kc < 4; kc++) {
      bf16x8 kf0 = *(const bf16x8*)&lK[cur][(((kc * 2 + hi) << 6) + l31) * 8];
      bf16x8 kf1 = *(const bf16x8*)&lK[cur][(((kc * 2 + hi) << 6) + 32 + l31) * 8];
      sacc0 = __builtin_amdgcn_mfma_f32_32x32x16_bf16(kf0, qf[kc], sacc0, 0, 0, 0);
      sacc1 = __builtin_amdgcn_mfma_f32_32x32x16_bf16(kf1, qf[kc], sacc1, 0, 0, 0);
    }
    __builtin_amdgcn_s_setprio(0);
    float z[32];
#pragma unroll
    for (int r = 0; r < 16; r++) { z[r] = sacc0[r]; z[16 + r] = sacc1[r]; }
    if (!fullTile) {
#pragma unroll
      for (int i = 0; i < 32; i++) {
        int kg = kv * 64 + (i >> 4) * 32 + (i & 3) + (((i & 15) >> 2) << 3) + (hi << 2);
        if (kg >= N) z[i] = -1e30f;
      }
    }
#pragma unroll
    for (int i = 0; i < 32; i++) z[i] = exp2f(z[i]);
#pragma unroll
    for (int kt = 0; kt < 2; kt++) {
      unsigned w0[4], w1[4];
#pragma unroll
      for (int rr = 0; rr < 4; rr++) {
        asm("v_cvt_pk_bf16_f32 %0, %1, %2" : "=v"(w0[rr]) : "v"(z[kt * 16 + 4 * rr]), "v"(z[kt * 16 + 4 * rr + 1]));
        asm("v_cvt_pk_bf16_f32 %0, %1, %2" : "=v"(w1[rr]) : "v"(z[kt * 16 + 4 * rr + 2]), "v"(z[kt * 16 + 4 * rr + 3]));
      }
#pragma unroll
      for (int kc2 = 0; kc2 < 2; kc2++) {
        unsigned ua = w0[2 * kc2], ub = w0[2 * kc2 + 1];
        unsigned uc = w1[2 * kc2], ud = w1[2 * kc2 + 1];
        asm("v_permlane32_swap_b32 %0, %1" : "+&v"(ua), "+v"(ub));
        asm("v_permlane32_swap_b32 %0, %1" : "+&v"(uc), "+v"(ud));
        union { unsigned u[4]; bf16x8 v; } pa;
        pa.u[0] = ua; pa.u[1] = uc; pa.u[2] = ub; pa.u[3] = ud;
        int kcg = kt * 2 + kc2;
        __builtin_amdgcn_s_setprio(1);
#pragma unroll
        for (int dt = 0; dt < 2; dt++) {
          bf16x8 vf = *(const bf16x8*)&lV[cur][(((kcg * 2 + hi) << 6) + dt * 32 + l31) * 8];
          oacc[dt] = __builtin_amdgcn_mfma_f32_32x32x16_bf16(pa.v, vf, oacc[dt], 0, 0, 0);
        }
        osum = __builtin_amdgcn_mfma_f32_32x32x16_bf16(pa.v, ones.v, osum, 0, 0, 0);
        __builtin_amdgcn_s_setprio(0);
      }
    }
    __syncthreads();
  }
#pragma unroll
  for (int r = 0; r < 16; r++) {
    int q = qb + wave * 32 + (r & 3) + ((r >> 2) << 3) + (hi << 2);
    if (q < N) {
      float inv;
      asm("v_rcp_f32 %0, %1" : "=v"(inv) : "v"(osum[r]));
      ushort* orow = o_out + (rowbase + (size_t)b * N + q) * 768 + h * 64;
      orow[l31] = f2bf(oacc[0][r] * inv);
      orow[32 + l31] = f2bf(oacc[1][r] * inv);
    }
  }
}

// ---------------- host-side orchestration (fused streams) ----------------
extern "C" void kernel_launch(void* const* d_in, const int* in_sizes, int n_in,
                              void* d_out, int out_size, void* d_ws, size_t ws_size,
                              hipStream_t stream) {
  const float* x1 = (const float*)d_in[0];
  const float* x2 = (const float*)d_in[1];
  const float* ln1_w = (const float*)d_in[2];
  const float* ln1_b = (const float*)d_in[3];
  const float* qkv_w = (const float*)d_in[4];
  const float* proj_w = (const float*)d_in[5];
  const float* proj_b = (const float*)d_in[6];
  const float* ln2_w = (const float*)d_in[7];
  const float* ln2_b = (const float*)d_in[8];
  const float* fc1_w = (const float*)d_in[9];
  const float* fc1_b = (const float*)d_in[10];
  const float* fc2_w = (const float*)d_in[11];
  const float* fc2_b = (const float*)d_in[12];
  float* out = (float*)d_out;

  const int N1 = 1370, N2 = 257;
  const int M1 = 8 * N1, M2 = 8 * N2;    // 10960, 2056
  const int MT = M1 + M2;                // 13016
  const int MPAD = 13056;                // 102*128 = 204*64
  const int nkv1 = 22, nkv2 = 5;

  char* ws = (char*)d_ws;
  ushort* wq = (ushort*)ws;   ws += (size_t)2304 * 768 * 2;
  ushort* wp = (ushort*)ws;   ws += (size_t)768 * 768 * 2;
  ushort* w1 = (ushort*)ws;   ws += (size_t)3072 * 768 * 2;
  ushort* w2 = (ushort*)ws;   ws += (size_t)768 * 3072 * 2;
  ushort* bufA = (ushort*)ws;   ws += (size_t)MPAD * 768 * 2;
  ushort* bufQKV = (ushort*)ws; ws += (size_t)MPAD * 2304 * 2;
  ushort* bufFF = (ushort*)ws;  ws += (size_t)MPAD * 3072 * 2;
  const size_t nTiles = (size_t)96 * (nkv1 + nkv2);
  ushort* kt2 = bufFF;
  ushort* vt2 = bufFF + nTiles * 4096;

  cvt4_kernel<<<2048, 256, 0, stream>>>(qkv_w, proj_w, fc1_w, fc2_w,
                                        2304 * 768, 768 * 768, 3072 * 768, 768 * 3072, wq);

  ln_kernel<<<(MT + 3) / 4, 256, 0, stream>>>(x1, x2, M1, MT, ln1_w, ln1_b, bufA);
  gemm_tile<0, 768, 18><<<(MPAD / 128) * 18, 512, 0, stream>>>(
      bufA, wq, nullptr, bufQKV, MT, 2304);
  prep_kernel<<<dim3(192, nkv1), 256, 0, stream>>>(bufQKV, kt2, vt2, N1, N2, nkv1, nkv2, M1);
  attn_kernel<<<dim3(192, 11), 256, 0, stream>>>(
      bufQKV, kt2, vt2, bufA, N1, N2, nkv1, nkv2, M1);
  gemm_tile64<768, 6><<<(MPAD / 64) * 6, 256, 0, stream>>>(
      bufA, wp, proj_b, x1, x2, M1, out, MT, 768);
  ln_kernel<<<(MT + 3) / 4, 256, 0, stream>>>(out, out, MT, MT, ln2_w, ln2_b, bufA);
  gemm_tile<2, 768, 24><<<(MPAD / 128) * 24, 512, 0, stream>>>(
      bufA, w1, fc1_b, bufFF, MT, 3072);
  gemm_tile64<3072, 6><<<(MPAD / 64) * 6, 256, 0, stream>>>(
      bufFF, w2, fc2_b, out, nullptr, MT, out, MT, 768);
}